// Round 6
// baseline (156.632 us; speedup 1.0000x reference)
//
#include <hip/hip_runtime.h>

#define ALPHA 0.2f
constexpr int N = 50000;
constexpr int E = 800000;

typedef __attribute__((ext_vector_type(8))) short bf16x8;
typedef __attribute__((ext_vector_type(4))) float f32x4;

__device__ inline ushort f2bf(float v) {
  uint u = __float_as_uint(v);
  return (ushort)((u + 0x7fff + ((u >> 16) & 1)) >> 16);  // RNE, finite inputs
}
__device__ inline float bf2f(ushort u) { return __uint_as_float(((uint)u) << 16); }

constexpr int LDX = 136;  // LDS row stride in bf16: 272 B -> 4-bank/row rotation, 16B-aligned

// -------------------- zero deg (hipMemsetAsync's fill kernel costs 42us in-graph!) --------------------
__global__ __launch_bounds__(256) void zero_deg_kernel(int4* __restrict__ deg4) {
  int i = blockIdx.x * blockDim.x + threadIdx.x;
  if (i < (N + 3) / 4) deg4[i] = make_int4(0, 0, 0, 0);
}

// -------------------- weight prep: fp32 [128][128] -> frag-ordered bf16 hi/lo --------------------
__global__ void wprep_kernel(const float* __restrict__ W1, const float* __restrict__ W2,
                             ushort* __restrict__ wf1hi, ushort* __restrict__ wf1lo,
                             ushort* __restrict__ wf2hi, ushort* __restrict__ wf2lo) {
  int t = blockIdx.x * blockDim.x + threadIdx.x;
  if (t >= 4096) return;
  const float* W = (t < 2048) ? W1 : W2;
  ushort* whi = (t < 2048) ? wf1hi : wf2hi;
  ushort* wlo = (t < 2048) ? wf1lo : wf2lo;
  int f = t & 2047;
  int ks = f >> 9, rem = f & 511, jb = rem >> 6, l = rem & 63;
  int m = jb * 16 + (l & 15), kb = ks * 32 + (l >> 4) * 8;
#pragma unroll
  for (int q = 0; q < 2; ++q) {
    float4 v = *(const float4*)&W[m * 128 + kb + q * 4];
    ushort4 hi, lo;
    hi.x = f2bf(v.x); lo.x = f2bf(v.x - bf2f(hi.x));
    hi.y = f2bf(v.y); lo.y = f2bf(v.y - bf2f(hi.y));
    hi.z = f2bf(v.z); lo.z = f2bf(v.z - bf2f(hi.z));
    hi.w = f2bf(v.w); lo.w = f2bf(v.w - bf2f(hi.w));
    *(ushort4*)&whi[f * 8 + q * 4] = hi;
    *(ushort4*)&wlo[f * 8 + q * 4] = lo;
  }
}

// -------------------- fused feature kernel (MFMA, hi/lo bf16 split) --------------------
__global__ __launch_bounds__(256) void feat_kernel(
    const float* __restrict__ x,
    const ushort* __restrict__ wf1hi, const ushort* __restrict__ wf1lo,
    const ushort* __restrict__ wf2hi, const ushort* __restrict__ wf2lo,
    const float* __restrict__ attn_l, const float* __restrict__ attn_r,
    ushort* __restrict__ ft_bf, float* __restrict__ a1, float* __restrict__ a2) {
  extern __shared__ char smem[];
  ushort* sXhi = (ushort*)smem;        // [64][LDX]
  ushort* sXlo = sXhi + 64 * LDX;
  const int tid = threadIdx.x;
  const int w = tid >> 6, l = tid & 63;
  const int lr = l & 15, lg4 = l >> 4;
  const int rowBase = blockIdx.x * 64;

  for (int i = tid; i < 64 * 32; i += 256) {
    int row = i >> 5, kc = i & 31;
    int g = rowBase + row;
    float4 v = make_float4(0.f, 0.f, 0.f, 0.f);
    if (g < N) v = reinterpret_cast<const float4*>(x)[g * 32 + kc];
    ushort4 hi, lo;
    hi.x = f2bf(v.x); lo.x = f2bf(v.x - bf2f(hi.x));
    hi.y = f2bf(v.y); lo.y = f2bf(v.y - bf2f(hi.y));
    hi.z = f2bf(v.z); lo.z = f2bf(v.z - bf2f(hi.z));
    hi.w = f2bf(v.w); lo.w = f2bf(v.w - bf2f(hi.w));
    *(ushort4*)&sXhi[row * LDX + kc * 4] = hi;
    *(ushort4*)&sXlo[row * LDX + kc * 4] = lo;
  }

  bf16x8 bh[4][2], bl[4][2];
#pragma unroll
  for (int ks = 0; ks < 4; ++ks)
#pragma unroll
    for (int jj = 0; jj < 2; ++jj) {
      int off = ((ks * 8 + (2 * w + jj)) * 64 + l) * 8;
      bh[ks][jj] = *(const bf16x8*)&wf1hi[off];
      bl[ks][jj] = *(const bf16x8*)&wf1lo[off];
    }
  __syncthreads();

  f32x4 acc[4][2];
#pragma unroll
  for (int mi = 0; mi < 4; ++mi)
#pragma unroll
    for (int jj = 0; jj < 2; ++jj) acc[mi][jj] = (f32x4){0.f, 0.f, 0.f, 0.f};

#pragma unroll
  for (int ks = 0; ks < 4; ++ks) {
    bf16x8 ah[4], al[4];
#pragma unroll
    for (int mi = 0; mi < 4; ++mi) {
      int addr = (mi * 16 + lr) * LDX + ks * 32 + lg4 * 8;
      ah[mi] = *(const bf16x8*)&sXhi[addr];
      al[mi] = *(const bf16x8*)&sXlo[addr];
    }
#pragma unroll
    for (int mi = 0; mi < 4; ++mi)
#pragma unroll
      for (int jj = 0; jj < 2; ++jj) {
        acc[mi][jj] = __builtin_amdgcn_mfma_f32_16x16x32_bf16(ah[mi], bh[ks][jj], acc[mi][jj], 0, 0, 0);
        acc[mi][jj] = __builtin_amdgcn_mfma_f32_16x16x32_bf16(ah[mi], bl[ks][jj], acc[mi][jj], 0, 0, 0);
        acc[mi][jj] = __builtin_amdgcn_mfma_f32_16x16x32_bf16(al[mi], bh[ks][jj], acc[mi][jj], 0, 0, 0);
      }
  }
  __syncthreads();

#pragma unroll
  for (int mi = 0; mi < 4; ++mi)
#pragma unroll
    for (int jj = 0; jj < 2; ++jj)
#pragma unroll
      for (int r = 0; r < 4; ++r) {
        float v = acc[mi][jj][r];
        v = v > 0.f ? v : ALPHA * v;
        int row = mi * 16 + lg4 * 4 + r;
        int col = w * 32 + jj * 16 + lr;
        ushort hv = f2bf(v);
        sXhi[row * LDX + col] = hv;
        sXlo[row * LDX + col] = f2bf(v - bf2f(hv));
      }
#pragma unroll
  for (int ks = 0; ks < 4; ++ks)
#pragma unroll
    for (int jj = 0; jj < 2; ++jj) {
      int off = ((ks * 8 + (2 * w + jj)) * 64 + l) * 8;
      bh[ks][jj] = *(const bf16x8*)&wf2hi[off];
      bl[ks][jj] = *(const bf16x8*)&wf2lo[off];
    }
  __syncthreads();

#pragma unroll
  for (int mi = 0; mi < 4; ++mi)
#pragma unroll
    for (int jj = 0; jj < 2; ++jj) acc[mi][jj] = (f32x4){0.f, 0.f, 0.f, 0.f};

#pragma unroll
  for (int ks = 0; ks < 4; ++ks) {
    bf16x8 ah[4], al[4];
#pragma unroll
    for (int mi = 0; mi < 4; ++mi) {
      int addr = (mi * 16 + lr) * LDX + ks * 32 + lg4 * 8;
      ah[mi] = *(const bf16x8*)&sXhi[addr];
      al[mi] = *(const bf16x8*)&sXlo[addr];
    }
#pragma unroll
    for (int mi = 0; mi < 4; ++mi)
#pragma unroll
      for (int jj = 0; jj < 2; ++jj) {
        acc[mi][jj] = __builtin_amdgcn_mfma_f32_16x16x32_bf16(ah[mi], bh[ks][jj], acc[mi][jj], 0, 0, 0);
        acc[mi][jj] = __builtin_amdgcn_mfma_f32_16x16x32_bf16(ah[mi], bl[ks][jj], acc[mi][jj], 0, 0, 0);
        acc[mi][jj] = __builtin_amdgcn_mfma_f32_16x16x32_bf16(al[mi], bh[ks][jj], acc[mi][jj], 0, 0, 0);
      }
  }

#pragma unroll
  for (int mi = 0; mi < 4; ++mi)
#pragma unroll
    for (int jj = 0; jj < 2; ++jj) {
      int h = 2 * w + jj;
      float alv = attn_l[h * 16 + lr], arv = attn_r[h * 16 + lr];
#pragma unroll
      for (int r = 0; r < 4; ++r) {
        float v = acc[mi][jj][r];
        int grow = rowBase + mi * 16 + lg4 * 4 + r;
        bool valid = grow < N;
        if (valid) ft_bf[grow * 128 + h * 16 + lr] = f2bf(v);
        float sl = v * alv, sr = v * arv;
#pragma unroll
        for (int off = 8; off; off >>= 1) {
          sl += __shfl_xor(sl, off, 16);
          sr += __shfl_xor(sr, off, 16);
        }
        if (valid && lr == 0) { a1[grow * 8 + h] = sl; a2[grow * 8 + h] = sr; }
      }
    }
}

// -------------------- CSR build --------------------
__global__ void hist_kernel(const int* __restrict__ dst, int* __restrict__ deg) {
  int i = blockIdx.x * blockDim.x + threadIdx.x;
  if (i < E) {
    unsigned d = (unsigned)dst[i];
    if (d < (unsigned)N) atomicAdd(&deg[d], 1);
  }
}

constexpr int SCH = 512;
constexpr int NCH = (N + SCH - 1) / SCH;       // 98
constexpr int BN  = 128;                       // nodes per bucket
constexpr int NB  = (N + BN - 1) / BN;         // 391 buckets
constexpr int NBP = 512;                       // padded for scan
constexpr int CHUNK = 2048;                    // edges per partition block

__global__ __launch_bounds__(SCH) void scanA_kernel(const int* __restrict__ deg,
    int* __restrict__ row_ptr, int* __restrict__ partial) {
  __shared__ int sh[SCH];
  const int t = threadIdx.x, b = blockIdx.x;
  const int i = b * SCH + t;
  int v = (i < N) ? deg[i] : 0;
  sh[t] = v;
  __syncthreads();
  for (int off = 1; off < SCH; off <<= 1) {
    int u = (t >= off) ? sh[t - off] : 0;
    __syncthreads();
    sh[t] += u;
    __syncthreads();
  }
  if (i < N) row_ptr[i] = sh[t] - v;
  if (t == SCH - 1) partial[b] = sh[SCH - 1];
}

__global__ __launch_bounds__(128) void scanB_kernel(const int* __restrict__ partial,
    int* __restrict__ partial_excl, int* __restrict__ row_ptr) {
  __shared__ int sh[128];
  const int t = threadIdx.x;
  int v = (t < NCH) ? partial[t] : 0;
  sh[t] = v;
  __syncthreads();
  for (int off = 1; off < 128; off <<= 1) {
    int u = (t >= off) ? sh[t - off] : 0;
    __syncthreads();
    sh[t] += u;
    __syncthreads();
  }
  if (t < NCH) partial_excl[t] = sh[t] - v;
  if (t == NCH - 1) row_ptr[N] = sh[t];
}

__global__ __launch_bounds__(SCH) void scanC_kernel(int* __restrict__ row_ptr,
    int* __restrict__ bucket_cursor, const int* __restrict__ partial_excl) {
  const int b = blockIdx.x;
  const int i = b * SCH + threadIdx.x;
  if (i < N) {
    int v = row_ptr[i] + partial_excl[b];
    row_ptr[i] = v;
    if ((i & (BN - 1)) == 0) bucket_cursor[i >> 7] = v;  // bucket base
  }
}

// ---- level-1 partition: block-local counting sort into 391 buckets, coalesced flush ----
// ebuf entry packed: (src << 7) | (dst & 127)   [src < 65536, fits]
__global__ __launch_bounds__(256) void part_kernel(const int* __restrict__ src,
    const int* __restrict__ dst, int* __restrict__ bucket_cursor, int* __restrict__ ebuf) {
  __shared__ int hist[NBP], sA[NBP], sB[NBP], curs[NBP], gbase[NBP];
  __shared__ int buf[CHUNK];
  const int t = threadIdx.x;
  const int e0 = blockIdx.x * CHUNK;
  const int e1 = min(e0 + CHUNK, E);
  for (int i = t; i < NBP; i += 256) hist[i] = 0;
  __syncthreads();
  for (int i = e0 + t; i < e1; i += 256)
    atomicAdd(&hist[((unsigned)dst[i]) >> 7], 1);
  __syncthreads();
  for (int k = t; k < NBP; k += 256) sA[k] = hist[k];
  __syncthreads();
  int* pin = sA; int* pout = sB;
  for (int off = 1; off < NBP; off <<= 1) {
    for (int k = t; k < NBP; k += 256)
      pout[k] = pin[k] + ((k >= off) ? pin[k - off] : 0);
    __syncthreads();
    int* tmp = pin; pin = pout; pout = tmp;
  }
  for (int k = t; k < NBP; k += 256) curs[k] = pin[k] - hist[k];  // exclusive
  __syncthreads();
  for (int i = e0 + t; i < e1; i += 256) {
    int s = src[i], d = dst[i];
    int p = atomicAdd(&curs[((unsigned)d) >> 7], 1);
    buf[p] = (s << 7) | (d & 127);
  }
  for (int b = t; b < NB; b += 256) {
    int h = hist[b];
    gbase[b] = h ? atomicAdd(&bucket_cursor[b], h) : 0;
  }
  __syncthreads();
  const int total = e1 - e0;
  for (int i = t; i < total; i += 256) {
    int lo = 0, hi = NB;
    while (lo < hi) { int m = (lo + hi) >> 1; if (pin[m] > i) hi = m; else lo = m + 1; }
    int rank = i - (pin[lo] - hist[lo]);
    ebuf[gbase[lo] + rank] = buf[i];
  }
}

// ---- level-2: per-bucket fine sort; one block owns one contiguous col_src region ----
__global__ __launch_bounds__(256) void fine_kernel(const int* __restrict__ ebuf,
    const int* __restrict__ row_ptr, int* __restrict__ col_src) {
  __shared__ int curs[BN];
  const int b = blockIdx.x, t = threadIdx.x;
  const int node0 = b * BN;
  const int node1 = min(node0 + BN, N);
  if (t < BN && node0 + t < node1) curs[t] = row_ptr[node0 + t];
  __syncthreads();
  const int estart = row_ptr[node0], eend = row_ptr[node1];
  for (int i = estart + t; i < eend; i += 256) {
    int pr = ebuf[i];
    int pos = atomicAdd(&curs[pr & 127], 1);
    col_src[pos] = pr >> 7;
  }
}

// -------------------- single-pass softmax-aggregate --------------------
// 64-lane group per node. Phase A: lane t=(edge e=t>>3, head hA=t&7) computes each
// (e,h) logit/exp exactly ONCE. Phase B: broadcast p and src via shfl; lane t
// accumulates d-pair t*2 (head hB=t>>3). 8 gathers in flight.
__global__ __launch_bounds__(256) void agg_kernel(const int* __restrict__ row_ptr,
    const int* __restrict__ col_src, const ushort* __restrict__ ft_bf,
    const float* __restrict__ a1, const float* __restrict__ a2,
    float* __restrict__ out) {
  const int node = blockIdx.x * 4 + (threadIdx.x >> 6);
  if (node >= N) return;
  const int t = threadIdx.x & 63;
  const int eSlot = t >> 3;
  const int hA = t & 7;
  const int hB = t >> 3;
  const int start = row_ptr[node], end = row_ptr[node + 1];
  const float a2nA = a2[node * 8 + hA];

  float l = 0.f, acc0 = 0.f, acc1 = 0.f;
  for (int base = start; base < end; base += 8) {
    int rem = end - base; rem = rem > 8 ? 8 : rem;
    int idx = base + (eSlot < rem ? eSlot : rem - 1);
    int s = col_src[idx];
    float lg = a1[s * 8 + hA] + a2nA;
    lg = lg > 0.f ? lg : ALPHA * lg;
    float p = (eSlot < rem) ? __expf(lg) : 0.f;
#pragma unroll
    for (int e = 0; e < 8; ++e) {
      float pe = __shfl(p, e * 8 + hB);
      int se = __shfl(s, e * 8);
      ushort2 f = *(const ushort2*)&ft_bf[se * 128 + t * 2];
      l += pe;
      acc0 = fmaf(pe, bf2f(f.x), acc0);
      acc1 = fmaf(pe, bf2f(f.y), acc1);
    }
  }
  float inv = (end > start) ? 1.f / l : 0.f;
  *(float2*)&out[node * 128 + t * 2] = make_float2(acc0 * inv, acc1 * inv);
}

// -------------------- launch --------------------
extern "C" void kernel_launch(void* const* d_in, const int* in_sizes, int n_in,
                              void* d_out, int out_size, void* d_ws, size_t ws_size,
                              hipStream_t stream) {
  const float* x      = (const float*)d_in[0];
  const float* W1     = (const float*)d_in[1];
  const float* W2     = (const float*)d_in[2];
  const float* attn_l = (const float*)d_in[3];
  const float* attn_r = (const float*)d_in[4];
  const int*   edge   = (const int*)d_in[5];
  const int*   src    = edge;
  const int*   dst    = edge + E;
  float* out = (float*)d_out;

  char* ws = (char*)d_ws;
  ushort* ft_bf         = (ushort*)(ws);                 // 12,800,000 B
  float*  a1            = (float*) (ws + 12800000);      //  1,600,000 B
  float*  a2            = (float*) (ws + 14400000);      //  1,600,000 B
  int*    row_ptr       = (int*)   (ws + 16000000);      //    200,064 B
  int*    deg           = (int*)   (ws + 16200064);      //    200,016 B (16B-aligned, N rounded to x4)
  int*    bucket_cursor = (int*)   (ws + 16400080);      //      2,048 B
  int*    partial       = (int*)   (ws + 16402128);      //        512 B
  int*    partial_excl  = (int*)   (ws + 16402640);      //        512 B
  int*    col_src       = (int*)   (ws + 16403152);      //  3,200,000 B
  ushort* wf1hi         = (ushort*)(ws + 19603152);      //     32,768 B each
  ushort* wf1lo         = (ushort*)(ws + 19635920);
  ushort* wf2hi         = (ushort*)(ws + 19668688);
  ushort* wf2lo         = (ushort*)(ws + 19701456);
  int*    ebuf          = (int*)   (ws + 19734224);      //  3,200,000 B -> end ~22.9 MB

  zero_deg_kernel<<<(N / 4 + 256) / 256, 256, 0, stream>>>((int4*)deg);
  wprep_kernel<<<16, 256, 0, stream>>>(W1, W2, wf1hi, wf1lo, wf2hi, wf2lo);
  feat_kernel<<<(N + 63) / 64, 256, 2 * 64 * LDX * sizeof(ushort), stream>>>(
      x, wf1hi, wf1lo, wf2hi, wf2lo, attn_l, attn_r, ft_bf, a1, a2);
  hist_kernel<<<(E + 255) / 256, 256, 0, stream>>>(dst, deg);
  scanA_kernel<<<NCH, SCH, 0, stream>>>(deg, row_ptr, partial);
  scanB_kernel<<<1, 128, 0, stream>>>(partial, partial_excl, row_ptr);
  scanC_kernel<<<NCH, SCH, 0, stream>>>(row_ptr, bucket_cursor, partial_excl);
  part_kernel<<<(E + CHUNK - 1) / CHUNK, 256, 0, stream>>>(src, dst, bucket_cursor, ebuf);
  fine_kernel<<<NB, 256, 0, stream>>>(ebuf, row_ptr, col_src);
  agg_kernel<<<(N + 3) / 4, 256, 0, stream>>>(row_ptr, col_src, ft_bf, a1, a2, out);
}

// Round 7
// 124.533 us; speedup vs baseline: 1.2578x; 1.2578x over previous
//
#include <hip/hip_runtime.h>

#define ALPHA 0.2f
constexpr int N = 50000;
constexpr int E = 800000;

typedef __attribute__((ext_vector_type(8))) short bf16x8;
typedef __attribute__((ext_vector_type(4))) float f32x4;

__device__ inline ushort f2bf(float v) {
  uint u = __float_as_uint(v);
  return (ushort)((u + 0x7fff + ((u >> 16) & 1)) >> 16);  // RNE, finite inputs
}
__device__ inline float bf2f(ushort u) { return __uint_as_float(((uint)u) << 16); }

constexpr int LDX = 136;  // LDS row stride in bf16: 272 B -> 4-bank/row rotation, 16B-aligned

constexpr int BN  = 128;                       // nodes per bucket
constexpr int NB  = (N + BN - 1) / BN;         // 391 buckets
constexpr int NBP = 512;                       // padded for scans
constexpr int CHUNK = 4096;                    // edges per part/bhist block
constexpr int NBLK  = (E + CHUNK - 1) / CHUNK; // 196

// -------------------- prep: weight conversion (blocks 0..15) + zero bucket_deg (block 16) ----
// frag slot f = (ks*8 + jb)*64 + l holds W[jb*16 + (l&15)][ks*32 + (l>>4)*8 + 0..7]
__global__ __launch_bounds__(256) void prep_kernel(const float* __restrict__ W1,
    const float* __restrict__ W2, ushort* __restrict__ wf1hi, ushort* __restrict__ wf1lo,
    ushort* __restrict__ wf2hi, ushort* __restrict__ wf2lo, int* __restrict__ bucket_deg) {
  if (blockIdx.x == 16) {
    for (int i = threadIdx.x; i < NB; i += 256) bucket_deg[i] = 0;
    return;
  }
  int t = blockIdx.x * 256 + threadIdx.x;
  const float* W = (t < 2048) ? W1 : W2;
  ushort* whi = (t < 2048) ? wf1hi : wf2hi;
  ushort* wlo = (t < 2048) ? wf1lo : wf2lo;
  int f = t & 2047;
  int ks = f >> 9, rem = f & 511, jb = rem >> 6, l = rem & 63;
  int m = jb * 16 + (l & 15), kb = ks * 32 + (l >> 4) * 8;
#pragma unroll
  for (int q = 0; q < 2; ++q) {
    float4 v = *(const float4*)&W[m * 128 + kb + q * 4];
    ushort4 hi, lo;
    hi.x = f2bf(v.x); lo.x = f2bf(v.x - bf2f(hi.x));
    hi.y = f2bf(v.y); lo.y = f2bf(v.y - bf2f(hi.y));
    hi.z = f2bf(v.z); lo.z = f2bf(v.z - bf2f(hi.z));
    hi.w = f2bf(v.w); lo.w = f2bf(v.w - bf2f(hi.w));
    *(ushort4*)&whi[f * 8 + q * 4] = hi;
    *(ushort4*)&wlo[f * 8 + q * 4] = lo;
  }
}

// -------------------- fused feature kernel (MFMA, hi/lo bf16 split) --------------------
__global__ __launch_bounds__(256) void feat_kernel(
    const float* __restrict__ x,
    const ushort* __restrict__ wf1hi, const ushort* __restrict__ wf1lo,
    const ushort* __restrict__ wf2hi, const ushort* __restrict__ wf2lo,
    const float* __restrict__ attn_l, const float* __restrict__ attn_r,
    ushort* __restrict__ ft_bf, float* __restrict__ a1, float* __restrict__ a2) {
  extern __shared__ char smem[];
  ushort* sXhi = (ushort*)smem;        // [64][LDX]
  ushort* sXlo = sXhi + 64 * LDX;
  const int tid = threadIdx.x;
  const int w = tid >> 6, l = tid & 63;
  const int lr = l & 15, lg4 = l >> 4;
  const int rowBase = blockIdx.x * 64;

  for (int i = tid; i < 64 * 32; i += 256) {
    int row = i >> 5, kc = i & 31;
    int g = rowBase + row;
    float4 v = make_float4(0.f, 0.f, 0.f, 0.f);
    if (g < N) v = reinterpret_cast<const float4*>(x)[g * 32 + kc];
    ushort4 hi, lo;
    hi.x = f2bf(v.x); lo.x = f2bf(v.x - bf2f(hi.x));
    hi.y = f2bf(v.y); lo.y = f2bf(v.y - bf2f(hi.y));
    hi.z = f2bf(v.z); lo.z = f2bf(v.z - bf2f(hi.z));
    hi.w = f2bf(v.w); lo.w = f2bf(v.w - bf2f(hi.w));
    *(ushort4*)&sXhi[row * LDX + kc * 4] = hi;
    *(ushort4*)&sXlo[row * LDX + kc * 4] = lo;
  }

  bf16x8 bh[4][2], bl[4][2];
#pragma unroll
  for (int ks = 0; ks < 4; ++ks)
#pragma unroll
    for (int jj = 0; jj < 2; ++jj) {
      int off = ((ks * 8 + (2 * w + jj)) * 64 + l) * 8;
      bh[ks][jj] = *(const bf16x8*)&wf1hi[off];
      bl[ks][jj] = *(const bf16x8*)&wf1lo[off];
    }
  __syncthreads();

  f32x4 acc[4][2];
#pragma unroll
  for (int mi = 0; mi < 4; ++mi)
#pragma unroll
    for (int jj = 0; jj < 2; ++jj) acc[mi][jj] = (f32x4){0.f, 0.f, 0.f, 0.f};

#pragma unroll
  for (int ks = 0; ks < 4; ++ks) {
    bf16x8 ah[4], al[4];
#pragma unroll
    for (int mi = 0; mi < 4; ++mi) {
      int addr = (mi * 16 + lr) * LDX + ks * 32 + lg4 * 8;
      ah[mi] = *(const bf16x8*)&sXhi[addr];
      al[mi] = *(const bf16x8*)&sXlo[addr];
    }
#pragma unroll
    for (int mi = 0; mi < 4; ++mi)
#pragma unroll
      for (int jj = 0; jj < 2; ++jj) {
        acc[mi][jj] = __builtin_amdgcn_mfma_f32_16x16x32_bf16(ah[mi], bh[ks][jj], acc[mi][jj], 0, 0, 0);
        acc[mi][jj] = __builtin_amdgcn_mfma_f32_16x16x32_bf16(ah[mi], bl[ks][jj], acc[mi][jj], 0, 0, 0);
        acc[mi][jj] = __builtin_amdgcn_mfma_f32_16x16x32_bf16(al[mi], bh[ks][jj], acc[mi][jj], 0, 0, 0);
      }
  }
  __syncthreads();

#pragma unroll
  for (int mi = 0; mi < 4; ++mi)
#pragma unroll
    for (int jj = 0; jj < 2; ++jj)
#pragma unroll
      for (int r = 0; r < 4; ++r) {
        float v = acc[mi][jj][r];
        v = v > 0.f ? v : ALPHA * v;
        int row = mi * 16 + lg4 * 4 + r;
        int col = w * 32 + jj * 16 + lr;
        ushort hv = f2bf(v);
        sXhi[row * LDX + col] = hv;
        sXlo[row * LDX + col] = f2bf(v - bf2f(hv));
      }
#pragma unroll
  for (int ks = 0; ks < 4; ++ks)
#pragma unroll
    for (int jj = 0; jj < 2; ++jj) {
      int off = ((ks * 8 + (2 * w + jj)) * 64 + l) * 8;
      bh[ks][jj] = *(const bf16x8*)&wf2hi[off];
      bl[ks][jj] = *(const bf16x8*)&wf2lo[off];
    }
  __syncthreads();

#pragma unroll
  for (int mi = 0; mi < 4; ++mi)
#pragma unroll
    for (int jj = 0; jj < 2; ++jj) acc[mi][jj] = (f32x4){0.f, 0.f, 0.f, 0.f};

#pragma unroll
  for (int ks = 0; ks < 4; ++ks) {
    bf16x8 ah[4], al[4];
#pragma unroll
    for (int mi = 0; mi < 4; ++mi) {
      int addr = (mi * 16 + lr) * LDX + ks * 32 + lg4 * 8;
      ah[mi] = *(const bf16x8*)&sXhi[addr];
      al[mi] = *(const bf16x8*)&sXlo[addr];
    }
#pragma unroll
    for (int mi = 0; mi < 4; ++mi)
#pragma unroll
      for (int jj = 0; jj < 2; ++jj) {
        acc[mi][jj] = __builtin_amdgcn_mfma_f32_16x16x32_bf16(ah[mi], bh[ks][jj], acc[mi][jj], 0, 0, 0);
        acc[mi][jj] = __builtin_amdgcn_mfma_f32_16x16x32_bf16(ah[mi], bl[ks][jj], acc[mi][jj], 0, 0, 0);
        acc[mi][jj] = __builtin_amdgcn_mfma_f32_16x16x32_bf16(al[mi], bh[ks][jj], acc[mi][jj], 0, 0, 0);
      }
  }

#pragma unroll
  for (int mi = 0; mi < 4; ++mi)
#pragma unroll
    for (int jj = 0; jj < 2; ++jj) {
      int h = 2 * w + jj;
      float alv = attn_l[h * 16 + lr], arv = attn_r[h * 16 + lr];
#pragma unroll
      for (int r = 0; r < 4; ++r) {
        float v = acc[mi][jj][r];
        int grow = rowBase + mi * 16 + lg4 * 4 + r;
        bool valid = grow < N;
        if (valid) ft_bf[grow * 128 + h * 16 + lr] = f2bf(v);
        float sl = v * alv, sr = v * arv;
#pragma unroll
        for (int off = 8; off; off >>= 1) {
          sl += __shfl_xor(sl, off, 16);
          sr += __shfl_xor(sr, off, 16);
        }
        if (valid && lr == 0) { a1[grow * 8 + h] = sl; a2[grow * 8 + h] = sr; }
      }
    }
}

// -------------------- bucket histogram: LDS per-block, 391 global adds/block ----------
__global__ __launch_bounds__(256) void bhist_kernel(const int* __restrict__ dst,
    int* __restrict__ bucket_deg) {
  __shared__ int lh[NB];
  const int t = threadIdx.x;
  const int e0 = blockIdx.x * CHUNK;
  const int e1 = min(e0 + CHUNK, E);
  for (int i = t; i < NB; i += 256) lh[i] = 0;
  __syncthreads();
  for (int i = e0 + t; i < e1; i += 256)
    atomicAdd(&lh[((unsigned)dst[i]) >> 7], 1);
  __syncthreads();
  for (int i = t; i < NB; i += 256) {
    int v = lh[i];
    if (v) atomicAdd(&bucket_deg[i], v);
  }
}

// -------------------- single-block scan of 391 bucket degrees ------------------------
__global__ __launch_bounds__(NBP) void scan391_kernel(const int* __restrict__ bucket_deg,
    int* __restrict__ bucket_base, int* __restrict__ bucket_cursor) {
  __shared__ int sh[NBP];
  const int t = threadIdx.x;
  int v = (t < NB) ? bucket_deg[t] : 0;
  sh[t] = v;
  __syncthreads();
  for (int off = 1; off < NBP; off <<= 1) {
    int u = (t >= off) ? sh[t - off] : 0;
    __syncthreads();
    sh[t] += u;
    __syncthreads();
  }
  if (t < NB) {
    int base = sh[t] - v;          // exclusive
    bucket_base[t] = base;
    bucket_cursor[t] = base;
  }
  if (t == NB - 1) bucket_base[NB] = sh[t];   // = E
}

// ---- level-1 partition: block-local counting sort into 391 buckets, coalesced flush ----
// ebuf entry packed: (src << 7) | (dst & 127)   [src < 65536, fits]
__global__ __launch_bounds__(256) void part_kernel(const int* __restrict__ src,
    const int* __restrict__ dst, int* __restrict__ bucket_cursor, int* __restrict__ ebuf) {
  __shared__ int hist[NBP], sA[NBP], sB[NBP], curs[NBP], gbase[NBP];
  __shared__ int buf[CHUNK];
  const int t = threadIdx.x;
  const int e0 = blockIdx.x * CHUNK;
  const int e1 = min(e0 + CHUNK, E);
  for (int i = t; i < NBP; i += 256) hist[i] = 0;
  __syncthreads();
  for (int i = e0 + t; i < e1; i += 256)
    atomicAdd(&hist[((unsigned)dst[i]) >> 7], 1);
  __syncthreads();
  for (int k = t; k < NBP; k += 256) sA[k] = hist[k];
  __syncthreads();
  int* pin = sA; int* pout = sB;
  for (int off = 1; off < NBP; off <<= 1) {
    for (int k = t; k < NBP; k += 256)
      pout[k] = pin[k] + ((k >= off) ? pin[k - off] : 0);
    __syncthreads();
    int* tmp = pin; pin = pout; pout = tmp;
  }
  for (int k = t; k < NBP; k += 256) curs[k] = pin[k] - hist[k];  // exclusive
  __syncthreads();
  for (int i = e0 + t; i < e1; i += 256) {
    int s = src[i], d = dst[i];
    int p = atomicAdd(&curs[((unsigned)d) >> 7], 1);
    buf[p] = (s << 7) | (d & 127);
  }
  for (int b = t; b < NB; b += 256) {
    int h = hist[b];
    gbase[b] = h ? atomicAdd(&bucket_cursor[b], h) : 0;
  }
  __syncthreads();
  const int total = e1 - e0;
  for (int i = t; i < total; i += 256) {
    int lo = 0, hi = NB;
    while (lo < hi) { int m = (lo + hi) >> 1; if (pin[m] > i) hi = m; else lo = m + 1; }
    int rank = i - (pin[lo] - hist[lo]);
    ebuf[gbase[lo] + rank] = buf[i];
  }
}

// ---- level-2: per-bucket fine sort + local CSR build (row_ptr derived here) ----------
__global__ __launch_bounds__(256) void fine_kernel(const int* __restrict__ ebuf,
    const int* __restrict__ bucket_base, int* __restrict__ row_ptr,
    int* __restrict__ col_src) {
  __shared__ int ldeg[BN], sc[BN], curs[BN];
  const int b = blockIdx.x, t = threadIdx.x;
  const int node0 = b * BN;
  const int nloc = min(BN, N - node0);
  const int bstart = bucket_base[b], bend = bucket_base[b + 1];
  if (t < BN) ldeg[t] = 0;
  __syncthreads();
  for (int i = bstart + t; i < bend; i += 256)
    atomicAdd(&ldeg[ebuf[i] & 127], 1);
  __syncthreads();
  if (t < BN) sc[t] = ldeg[t];
  __syncthreads();
#pragma unroll
  for (int off = 1; off < BN; off <<= 1) {
    int u = (t < BN && t >= off) ? sc[t - off] : 0;
    __syncthreads();
    if (t < BN) sc[t] += u;
    __syncthreads();
  }
  if (t < nloc) {
    int base = bstart + sc[t] - ldeg[t];
    row_ptr[node0 + t] = base;
    curs[t] = base;
  }
  if (b == NB - 1 && t == 0) row_ptr[N] = bend;
  __syncthreads();
  for (int i = bstart + t; i < bend; i += 256) {
    int pr = ebuf[i];
    int pos = atomicAdd(&curs[pr & 127], 1);
    col_src[pos] = pr >> 7;
  }
}

// -------------------- single-pass softmax-aggregate --------------------
// 64-lane group per node. Phase A: lane t=(edge e=t>>3, head hA=t&7) computes each
// (e,h) logit/exp exactly ONCE. Phase B: broadcast p and src via shfl; lane t
// accumulates d-pair t*2 (head hB=t>>3). 8 gathers in flight.
__global__ __launch_bounds__(256) void agg_kernel(const int* __restrict__ row_ptr,
    const int* __restrict__ col_src, const ushort* __restrict__ ft_bf,
    const float* __restrict__ a1, const float* __restrict__ a2,
    float* __restrict__ out) {
  const int node = blockIdx.x * 4 + (threadIdx.x >> 6);
  if (node >= N) return;
  const int t = threadIdx.x & 63;
  const int eSlot = t >> 3;
  const int hA = t & 7;
  const int hB = t >> 3;
  const int start = row_ptr[node], end = row_ptr[node + 1];
  const float a2nA = a2[node * 8 + hA];

  float l = 0.f, acc0 = 0.f, acc1 = 0.f;
  for (int base = start; base < end; base += 8) {
    int rem = end - base; rem = rem > 8 ? 8 : rem;
    int idx = base + (eSlot < rem ? eSlot : rem - 1);
    int s = col_src[idx];
    float lg = a1[s * 8 + hA] + a2nA;
    lg = lg > 0.f ? lg : ALPHA * lg;
    float p = (eSlot < rem) ? __expf(lg) : 0.f;
#pragma unroll
    for (int e = 0; e < 8; ++e) {
      float pe = __shfl(p, e * 8 + hB);
      int se = __shfl(s, e * 8);
      ushort2 f = *(const ushort2*)&ft_bf[se * 128 + t * 2];
      l += pe;
      acc0 = fmaf(pe, bf2f(f.x), acc0);
      acc1 = fmaf(pe, bf2f(f.y), acc1);
    }
  }
  float inv = (end > start) ? 1.f / l : 0.f;
  *(float2*)&out[node * 128 + t * 2] = make_float2(acc0 * inv, acc1 * inv);
}

// -------------------- launch --------------------
extern "C" void kernel_launch(void* const* d_in, const int* in_sizes, int n_in,
                              void* d_out, int out_size, void* d_ws, size_t ws_size,
                              hipStream_t stream) {
  const float* x      = (const float*)d_in[0];
  const float* W1     = (const float*)d_in[1];
  const float* W2     = (const float*)d_in[2];
  const float* attn_l = (const float*)d_in[3];
  const float* attn_r = (const float*)d_in[4];
  const int*   edge   = (const int*)d_in[5];
  const int*   src    = edge;
  const int*   dst    = edge + E;
  float* out = (float*)d_out;

  char* ws = (char*)d_ws;
  ushort* ft_bf         = (ushort*)(ws);                 // 12,800,000 B
  float*  a1            = (float*) (ws + 12800000);      //  1,600,000 B
  float*  a2            = (float*) (ws + 14400000);      //  1,600,000 B
  int*    row_ptr       = (int*)   (ws + 16000000);      //    200,064 B (N+1 ints)
  int*    bucket_deg    = (int*)   (ws + 16200064);      //      1,600 B (391, padded)
  int*    bucket_base   = (int*)   (ws + 16201664);      //      1,600 B (392, padded)
  int*    bucket_cursor = (int*)   (ws + 16203264);      //      1,600 B
  int*    col_src       = (int*)   (ws + 16204864);      //  3,200,000 B
  ushort* wf1hi         = (ushort*)(ws + 19404864);      //     32,768 B each
  ushort* wf1lo         = (ushort*)(ws + 19437632);
  ushort* wf2hi         = (ushort*)(ws + 19470400);
  ushort* wf2lo         = (ushort*)(ws + 19503168);
  int*    ebuf          = (int*)   (ws + 19535936);      //  3,200,000 B -> end ~22.7 MB

  prep_kernel<<<17, 256, 0, stream>>>(W1, W2, wf1hi, wf1lo, wf2hi, wf2lo, bucket_deg);
  feat_kernel<<<(N + 63) / 64, 256, 2 * 64 * LDX * sizeof(ushort), stream>>>(
      x, wf1hi, wf1lo, wf2hi, wf2lo, attn_l, attn_r, ft_bf, a1, a2);
  bhist_kernel<<<NBLK, 256, 0, stream>>>(dst, bucket_deg);
  scan391_kernel<<<1, NBP, 0, stream>>>(bucket_deg, bucket_base, bucket_cursor);
  part_kernel<<<NBLK, 256, 0, stream>>>(src, dst, bucket_cursor, ebuf);
  fine_kernel<<<NB, 256, 0, stream>>>(ebuf, bucket_base, row_ptr, col_src);
  agg_kernel<<<(N + 3) / 4, 256, 0, stream>>>(row_ptr, col_src, ft_bf, a1, a2, out);
}

// Round 8
// 104.071 us; speedup vs baseline: 1.5051x; 1.1966x over previous
//
#include <hip/hip_runtime.h>

#define ALPHA 0.2f
constexpr int N = 50000;
constexpr int E = 800000;

typedef __attribute__((ext_vector_type(8))) short bf16x8;
typedef __attribute__((ext_vector_type(4))) float f32x4;

__device__ inline ushort f2bf(float v) {
  uint u = __float_as_uint(v);
  return (ushort)((u + 0x7fff + ((u >> 16) & 1)) >> 16);  // RNE, finite inputs
}
__device__ inline float bf2f(ushort u) { return __uint_as_float(((uint)u) << 16); }

constexpr int LDX = 136;  // LDS row stride in bf16: 272 B -> 4-bank/row rotation, 16B-aligned

constexpr int BN   = 128;                       // nodes per bucket
constexpr int NB   = (N + BN - 1) / BN;         // 391 buckets
constexpr int NBP  = 512;                       // padded for scans
constexpr int PSTR = 392;                       // partial row stride (ints)
constexpr int CHUNK = 4096;                     // edges per part/bhist block
constexpr int NBLK  = (E + CHUNK - 1) / CHUNK;  // 196
constexpr int FEATB = (N + 63) / 64;            // 782 feat blocks

// -------------------- K1: bhist partials (blocks 0..195) + weight prep (196..211) ----
// frag slot f = (ks*8 + jb)*64 + l holds W[jb*16 + (l&15)][ks*32 + (l>>4)*8 + 0..7]
__global__ __launch_bounds__(256) void k1_kernel(const float* __restrict__ W1,
    const float* __restrict__ W2, ushort* __restrict__ wf1hi, ushort* __restrict__ wf1lo,
    ushort* __restrict__ wf2hi, ushort* __restrict__ wf2lo,
    const int* __restrict__ dst, int* __restrict__ partial) {
  const int bid = blockIdx.x;
  const int t = threadIdx.x;
  if (bid < NBLK) {
    __shared__ int lh[NB];
    const int e0 = bid * CHUNK, e1 = min(e0 + CHUNK, E);
    for (int i = t; i < NB; i += 256) lh[i] = 0;
    __syncthreads();
    for (int i = e0 + t; i < e1; i += 256)
      atomicAdd(&lh[((unsigned)dst[i]) >> 7], 1);
    __syncthreads();
    for (int i = t; i < NB; i += 256) partial[bid * PSTR + i] = lh[i];
    return;
  }
  int g = (bid - NBLK) * 256 + t;          // 0..4095
  const float* W = (g < 2048) ? W1 : W2;
  ushort* whi = (g < 2048) ? wf1hi : wf2hi;
  ushort* wlo = (g < 2048) ? wf1lo : wf2lo;
  int f = g & 2047;
  int ks = f >> 9, rem = f & 511, jb = rem >> 6, l = rem & 63;
  int m = jb * 16 + (l & 15), kb = ks * 32 + (l >> 4) * 8;
#pragma unroll
  for (int q = 0; q < 2; ++q) {
    float4 v = *(const float4*)&W[m * 128 + kb + q * 4];
    ushort4 hi, lo;
    hi.x = f2bf(v.x); lo.x = f2bf(v.x - bf2f(hi.x));
    hi.y = f2bf(v.y); lo.y = f2bf(v.y - bf2f(hi.y));
    hi.z = f2bf(v.z); lo.z = f2bf(v.z - bf2f(hi.z));
    hi.w = f2bf(v.w); lo.w = f2bf(v.w - bf2f(hi.w));
    *(ushort4*)&whi[f * 8 + q * 4] = hi;
    *(ushort4*)&wlo[f * 8 + q * 4] = lo;
  }
}

// -------------------- K2: column-sum + scan -> bucket_base, chunk_base ---------------
__global__ __launch_bounds__(NBP) void colscan_kernel(const int* __restrict__ partial,
    int* __restrict__ bucket_base, int* __restrict__ chunk_base) {
  __shared__ int sh[NBP];
  const int t = threadIdx.x;
  int tot = 0;
  if (t < NB)
    for (int blk = 0; blk < NBLK; ++blk) tot += partial[blk * PSTR + t];
  sh[t] = (t < NB) ? tot : 0;
  __syncthreads();
  for (int off = 1; off < NBP; off <<= 1) {
    int u = (t >= off) ? sh[t - off] : 0;
    __syncthreads();
    sh[t] += u;
    __syncthreads();
  }
  if (t < NB) {
    int base = sh[t] - tot;  // exclusive
    bucket_base[t] = base;
    int run = base;
    for (int blk = 0; blk < NBLK; ++blk) {
      chunk_base[blk * PSTR + t] = run;
      run += partial[blk * PSTR + t];
    }
  }
  if (t == NB - 1) bucket_base[NB] = sh[t];  // = E
}

// -------------------- K3: part (blocks 0..195) UNION feat (blocks 196..977) ----------
__global__ __launch_bounds__(256) void featpart_kernel(
    const float* __restrict__ x,
    const ushort* __restrict__ wf1hi, const ushort* __restrict__ wf1lo,
    const ushort* __restrict__ wf2hi, const ushort* __restrict__ wf2lo,
    const float* __restrict__ attn_l, const float* __restrict__ attn_r,
    ushort* __restrict__ ft_bf, float* __restrict__ a1, float* __restrict__ a2,
    const int* __restrict__ src, const int* __restrict__ dst,
    const int* __restrict__ partial, const int* __restrict__ chunk_base,
    int* __restrict__ ebuf) {
  extern __shared__ char smem[];
  const int bid = blockIdx.x;
  const int tid = threadIdx.x;

  if (bid < NBLK) {
    // ======== part: local counting sort into buckets, atomic-free global placement ====
    int* hist = (int*)smem;          // [512]
    int* sA   = hist + NBP;          // [512]
    int* sB   = sA + NBP;            // [512]
    int* curs = sB + NBP;            // [512]
    int* buf  = curs + NBP;          // [4096]
    const int e0 = bid * CHUNK, e1 = min(e0 + CHUNK, E);
    for (int k = tid; k < NBP; k += 256) {
      int h = (k < NB) ? partial[bid * PSTR + k] : 0;
      hist[k] = h;
      sA[k] = h;
    }
    __syncthreads();
    int* pin = sA; int* pout = sB;
    for (int off = 1; off < NBP; off <<= 1) {
      for (int k = tid; k < NBP; k += 256)
        pout[k] = pin[k] + ((k >= off) ? pin[k - off] : 0);
      __syncthreads();
      int* tmp = pin; pin = pout; pout = tmp;
    }
    for (int k = tid; k < NBP; k += 256) curs[k] = pin[k] - hist[k];  // exclusive
    __syncthreads();
    for (int i = e0 + tid; i < e1; i += 256) {
      int s = src[i], d = dst[i];
      int p = atomicAdd(&curs[((unsigned)d) >> 7], 1);
      buf[p] = (s << 7) | (d & 127);
    }
    __syncthreads();
    const int total = e1 - e0;
    for (int i = tid; i < total; i += 256) {
      int lo = 0, hi = NB;
      while (lo < hi) { int m = (lo + hi) >> 1; if (pin[m] > i) hi = m; else lo = m + 1; }
      int rank = i - (pin[lo] - hist[lo]);
      ebuf[chunk_base[bid * PSTR + lo] + rank] = buf[i];
    }
    return;
  }

  // ======== feat: ft = lrelu(x@W1^T)@W2^T (bf16 hi/lo MFMA), a1/a2 reductions ========
  ushort* sXhi = (ushort*)smem;        // [64][LDX]
  ushort* sXlo = sXhi + 64 * LDX;
  const int w = tid >> 6, l = tid & 63;
  const int lr = l & 15, lg4 = l >> 4;
  const int rowBase = (bid - NBLK) * 64;

  for (int i = tid; i < 64 * 32; i += 256) {
    int row = i >> 5, kc = i & 31;
    int g = rowBase + row;
    float4 v = make_float4(0.f, 0.f, 0.f, 0.f);
    if (g < N) v = reinterpret_cast<const float4*>(x)[g * 32 + kc];
    ushort4 hi, lo;
    hi.x = f2bf(v.x); lo.x = f2bf(v.x - bf2f(hi.x));
    hi.y = f2bf(v.y); lo.y = f2bf(v.y - bf2f(hi.y));
    hi.z = f2bf(v.z); lo.z = f2bf(v.z - bf2f(hi.z));
    hi.w = f2bf(v.w); lo.w = f2bf(v.w - bf2f(hi.w));
    *(ushort4*)&sXhi[row * LDX + kc * 4] = hi;
    *(ushort4*)&sXlo[row * LDX + kc * 4] = lo;
  }

  bf16x8 bh[4][2], bl[4][2];
#pragma unroll
  for (int ks = 0; ks < 4; ++ks)
#pragma unroll
    for (int jj = 0; jj < 2; ++jj) {
      int off = ((ks * 8 + (2 * w + jj)) * 64 + l) * 8;
      bh[ks][jj] = *(const bf16x8*)&wf1hi[off];
      bl[ks][jj] = *(const bf16x8*)&wf1lo[off];
    }
  __syncthreads();

  f32x4 acc[4][2];
#pragma unroll
  for (int mi = 0; mi < 4; ++mi)
#pragma unroll
    for (int jj = 0; jj < 2; ++jj) acc[mi][jj] = (f32x4){0.f, 0.f, 0.f, 0.f};

#pragma unroll
  for (int ks = 0; ks < 4; ++ks) {
    bf16x8 ah[4], al[4];
#pragma unroll
    for (int mi = 0; mi < 4; ++mi) {
      int addr = (mi * 16 + lr) * LDX + ks * 32 + lg4 * 8;
      ah[mi] = *(const bf16x8*)&sXhi[addr];
      al[mi] = *(const bf16x8*)&sXlo[addr];
    }
#pragma unroll
    for (int mi = 0; mi < 4; ++mi)
#pragma unroll
      for (int jj = 0; jj < 2; ++jj) {
        acc[mi][jj] = __builtin_amdgcn_mfma_f32_16x16x32_bf16(ah[mi], bh[ks][jj], acc[mi][jj], 0, 0, 0);
        acc[mi][jj] = __builtin_amdgcn_mfma_f32_16x16x32_bf16(ah[mi], bl[ks][jj], acc[mi][jj], 0, 0, 0);
        acc[mi][jj] = __builtin_amdgcn_mfma_f32_16x16x32_bf16(al[mi], bh[ks][jj], acc[mi][jj], 0, 0, 0);
      }
  }
  __syncthreads();

#pragma unroll
  for (int mi = 0; mi < 4; ++mi)
#pragma unroll
    for (int jj = 0; jj < 2; ++jj)
#pragma unroll
      for (int r = 0; r < 4; ++r) {
        float v = acc[mi][jj][r];
        v = v > 0.f ? v : ALPHA * v;
        int row = mi * 16 + lg4 * 4 + r;
        int col = w * 32 + jj * 16 + lr;
        ushort hv = f2bf(v);
        sXhi[row * LDX + col] = hv;
        sXlo[row * LDX + col] = f2bf(v - bf2f(hv));
      }
#pragma unroll
  for (int ks = 0; ks < 4; ++ks)
#pragma unroll
    for (int jj = 0; jj < 2; ++jj) {
      int off = ((ks * 8 + (2 * w + jj)) * 64 + l) * 8;
      bh[ks][jj] = *(const bf16x8*)&wf2hi[off];
      bl[ks][jj] = *(const bf16x8*)&wf2lo[off];
    }
  __syncthreads();

#pragma unroll
  for (int mi = 0; mi < 4; ++mi)
#pragma unroll
    for (int jj = 0; jj < 2; ++jj) acc[mi][jj] = (f32x4){0.f, 0.f, 0.f, 0.f};

#pragma unroll
  for (int ks = 0; ks < 4; ++ks) {
    bf16x8 ah[4], al[4];
#pragma unroll
    for (int mi = 0; mi < 4; ++mi) {
      int addr = (mi * 16 + lr) * LDX + ks * 32 + lg4 * 8;
      ah[mi] = *(const bf16x8*)&sXhi[addr];
      al[mi] = *(const bf16x8*)&sXlo[addr];
    }
#pragma unroll
    for (int mi = 0; mi < 4; ++mi)
#pragma unroll
      for (int jj = 0; jj < 2; ++jj) {
        acc[mi][jj] = __builtin_amdgcn_mfma_f32_16x16x32_bf16(ah[mi], bh[ks][jj], acc[mi][jj], 0, 0, 0);
        acc[mi][jj] = __builtin_amdgcn_mfma_f32_16x16x32_bf16(ah[mi], bl[ks][jj], acc[mi][jj], 0, 0, 0);
        acc[mi][jj] = __builtin_amdgcn_mfma_f32_16x16x32_bf16(al[mi], bh[ks][jj], acc[mi][jj], 0, 0, 0);
      }
  }

#pragma unroll
  for (int mi = 0; mi < 4; ++mi)
#pragma unroll
    for (int jj = 0; jj < 2; ++jj) {
      int h = 2 * w + jj;
      float alv = attn_l[h * 16 + lr], arv = attn_r[h * 16 + lr];
#pragma unroll
      for (int r = 0; r < 4; ++r) {
        float v = acc[mi][jj][r];
        int grow = rowBase + mi * 16 + lg4 * 4 + r;
        bool valid = grow < N;
        if (valid) ft_bf[grow * 128 + h * 16 + lr] = f2bf(v);
        float sl = v * alv, sr = v * arv;
#pragma unroll
        for (int off = 8; off; off >>= 1) {
          sl += __shfl_xor(sl, off, 16);
          sr += __shfl_xor(sr, off, 16);
        }
        if (valid && lr == 0) { a1[grow * 8 + h] = sl; a2[grow * 8 + h] = sr; }
      }
    }
}

// ---- K4: per-bucket fine sort + local CSR build (row_ptr derived here) --------------
__global__ __launch_bounds__(256) void fine_kernel(const int* __restrict__ ebuf,
    const int* __restrict__ bucket_base, int* __restrict__ row_ptr,
    int* __restrict__ col_src) {
  __shared__ int ldeg[BN], sc[BN], curs[BN];
  const int b = blockIdx.x, t = threadIdx.x;
  const int node0 = b * BN;
  const int nloc = min(BN, N - node0);
  const int bstart = bucket_base[b], bend = bucket_base[b + 1];
  if (t < BN) ldeg[t] = 0;
  __syncthreads();
  for (int i = bstart + t; i < bend; i += 256)
    atomicAdd(&ldeg[ebuf[i] & 127], 1);
  __syncthreads();
  if (t < BN) sc[t] = ldeg[t];
  __syncthreads();
#pragma unroll
  for (int off = 1; off < BN; off <<= 1) {
    int u = (t < BN && t >= off) ? sc[t - off] : 0;
    __syncthreads();
    if (t < BN) sc[t] += u;
    __syncthreads();
  }
  if (t < nloc) {
    int base = bstart + sc[t] - ldeg[t];
    row_ptr[node0 + t] = base;
    curs[t] = base;
  }
  if (b == NB - 1 && t == 0) row_ptr[N] = bend;
  __syncthreads();
  for (int i = bstart + t; i < bend; i += 256) {
    int pr = ebuf[i];
    int pos = atomicAdd(&curs[pr & 127], 1);
    col_src[pos] = pr >> 7;
  }
}

// -------------------- K5: single-pass softmax-aggregate ------------------------------
// 64-lane group per node. Phase A: lane t=(edge e=t>>3, head hA=t&7) computes each
// (e,h) logit/exp exactly ONCE. Phase B: broadcast p and src via shfl; lane t
// accumulates d-pair t*2 (head hB=t>>3). 8 gathers in flight.
__global__ __launch_bounds__(256) void agg_kernel(const int* __restrict__ row_ptr,
    const int* __restrict__ col_src, const ushort* __restrict__ ft_bf,
    const float* __restrict__ a1, const float* __restrict__ a2,
    float* __restrict__ out) {
  const int node = blockIdx.x * 4 + (threadIdx.x >> 6);
  if (node >= N) return;
  const int t = threadIdx.x & 63;
  const int eSlot = t >> 3;
  const int hA = t & 7;
  const int hB = t >> 3;
  const int start = row_ptr[node], end = row_ptr[node + 1];
  const float a2nA = a2[node * 8 + hA];

  float l = 0.f, acc0 = 0.f, acc1 = 0.f;
  for (int base = start; base < end; base += 8) {
    int rem = end - base; rem = rem > 8 ? 8 : rem;
    int idx = base + (eSlot < rem ? eSlot : rem - 1);
    int s = col_src[idx];
    float lg = a1[s * 8 + hA] + a2nA;
    lg = lg > 0.f ? lg : ALPHA * lg;
    float p = (eSlot < rem) ? __expf(lg) : 0.f;
#pragma unroll
    for (int e = 0; e < 8; ++e) {
      float pe = __shfl(p, e * 8 + hB);
      int se = __shfl(s, e * 8);
      ushort2 f = *(const ushort2*)&ft_bf[se * 128 + t * 2];
      l += pe;
      acc0 = fmaf(pe, bf2f(f.x), acc0);
      acc1 = fmaf(pe, bf2f(f.y), acc1);
    }
  }
  float inv = (end > start) ? 1.f / l : 0.f;
  *(float2*)&out[node * 128 + t * 2] = make_float2(acc0 * inv, acc1 * inv);
}

// -------------------- launch --------------------
extern "C" void kernel_launch(void* const* d_in, const int* in_sizes, int n_in,
                              void* d_out, int out_size, void* d_ws, size_t ws_size,
                              hipStream_t stream) {
  const float* x      = (const float*)d_in[0];
  const float* W1     = (const float*)d_in[1];
  const float* W2     = (const float*)d_in[2];
  const float* attn_l = (const float*)d_in[3];
  const float* attn_r = (const float*)d_in[4];
  const int*   edge   = (const int*)d_in[5];
  const int*   src    = edge;
  const int*   dst    = edge + E;
  float* out = (float*)d_out;

  char* ws = (char*)d_ws;
  ushort* ft_bf       = (ushort*)(ws);                 // 12,800,000 B
  float*  a1          = (float*) (ws + 12800000);      //  1,600,000 B
  float*  a2          = (float*) (ws + 14400000);      //  1,600,000 B
  int*    row_ptr     = (int*)   (ws + 16000000);      //    200,064 B (N+1 ints)
  int*    bucket_base = (int*)   (ws + 16200064);      //      1,600 B (392 ints)
  int*    col_src     = (int*)   (ws + 16201664);      //  3,200,000 B
  ushort* wf1hi       = (ushort*)(ws + 19401664);      //     32,768 B each
  ushort* wf1lo       = (ushort*)(ws + 19434432);
  ushort* wf2hi       = (ushort*)(ws + 19467200);
  ushort* wf2lo       = (ushort*)(ws + 19499968);
  int*    ebuf        = (int*)   (ws + 19532736);      //  3,200,000 B
  int*    partial     = (int*)   (ws + 22732736);      //    307,328 B (196x392 ints)
  int*    chunk_base  = (int*)   (ws + 23040064);      //    307,328 B -> end ~23.35 MB

  k1_kernel<<<NBLK + 16, 256, 0, stream>>>(W1, W2, wf1hi, wf1lo, wf2hi, wf2lo, dst, partial);
  colscan_kernel<<<1, NBP, 0, stream>>>(partial, bucket_base, chunk_base);
  featpart_kernel<<<NBLK + FEATB, 256, 2 * 64 * LDX * sizeof(ushort), stream>>>(
      x, wf1hi, wf1lo, wf2hi, wf2lo, attn_l, attn_r, ft_bf, a1, a2,
      src, dst, partial, chunk_base, ebuf);
  fine_kernel<<<NB, 256, 0, stream>>>(ebuf, bucket_base, row_ptr, col_src);
  agg_kernel<<<(N + 3) / 4, 256, 0, stream>>>(row_ptr, col_src, ft_bf, a1, a2, out);
}

// Round 9
// 98.449 us; speedup vs baseline: 1.5910x; 1.0571x over previous
//
#include <hip/hip_runtime.h>

#define ALPHA 0.2f
constexpr int N = 50000;
constexpr int E = 800000;

typedef __attribute__((ext_vector_type(8))) short bf16x8;
typedef __attribute__((ext_vector_type(4))) float f32x4;

__device__ inline ushort f2bf(float v) {
  uint u = __float_as_uint(v);
  return (ushort)((u + 0x7fff + ((u >> 16) & 1)) >> 16);  // RNE, finite inputs
}
__device__ inline float bf2f(ushort u) { return __uint_as_float(((uint)u) << 16); }

constexpr int LDX = 136;  // LDS row stride in bf16: 272 B -> 4-bank/row rotation, 16B-aligned

constexpr int BN   = 128;                       // nodes per bucket
constexpr int NB   = (N + BN - 1) / BN;         // 391 buckets
constexpr int NBP  = 512;                       // padded for scans
constexpr int PSTR = 392;                       // partial row stride (ints)
constexpr int CHUNK = 4096;                     // edges per part/bhist block
constexpr int NBLK  = (E + CHUNK - 1) / CHUNK;  // 196
constexpr int FROWS = 32;                       // feat tile rows
constexpr int FEATB = (N + FROWS - 1) / FROWS;  // 1563 feat blocks
constexpr int SMEMB = 2 * FROWS * LDX * 2;      // 17408 B dynamic LDS

// -------------------- K1: bhist partials (blocks 0..195) + weight prep (196..211) ----
// frag slot f = (ks*8 + jb)*64 + l holds W[jb*16 + (l&15)][ks*32 + (l>>4)*8 + 0..7]
__global__ __launch_bounds__(256) void k1_kernel(const float* __restrict__ W1,
    const float* __restrict__ W2, ushort* __restrict__ wf1hi, ushort* __restrict__ wf1lo,
    ushort* __restrict__ wf2hi, ushort* __restrict__ wf2lo,
    const int* __restrict__ dst, int* __restrict__ partial) {
  const int bid = blockIdx.x;
  const int t = threadIdx.x;
  if (bid < NBLK) {
    __shared__ int lh[NB];
    const int e0 = bid * CHUNK, e1 = min(e0 + CHUNK, E);
    for (int i = t; i < NB; i += 256) lh[i] = 0;
    __syncthreads();
    for (int i = e0 + t; i < e1; i += 256)
      atomicAdd(&lh[((unsigned)dst[i]) >> 7], 1);
    __syncthreads();
    for (int i = t; i < NB; i += 256) partial[bid * PSTR + i] = lh[i];
    return;
  }
  int g = (bid - NBLK) * 256 + t;          // 0..4095
  const float* W = (g < 2048) ? W1 : W2;
  ushort* whi = (g < 2048) ? wf1hi : wf2hi;
  ushort* wlo = (g < 2048) ? wf1lo : wf2lo;
  int f = g & 2047;
  int ks = f >> 9, rem = f & 511, jb = rem >> 6, l = rem & 63;
  int m = jb * 16 + (l & 15), kb = ks * 32 + (l >> 4) * 8;
#pragma unroll
  for (int q = 0; q < 2; ++q) {
    float4 v = *(const float4*)&W[m * 128 + kb + q * 4];
    ushort4 hi, lo;
    hi.x = f2bf(v.x); lo.x = f2bf(v.x - bf2f(hi.x));
    hi.y = f2bf(v.y); lo.y = f2bf(v.y - bf2f(hi.y));
    hi.z = f2bf(v.z); lo.z = f2bf(v.z - bf2f(hi.z));
    hi.w = f2bf(v.w); lo.w = f2bf(v.w - bf2f(hi.w));
    *(ushort4*)&whi[f * 8 + q * 4] = hi;
    *(ushort4*)&wlo[f * 8 + q * 4] = lo;
  }
}

// -------------------- K2: column-sum + scan -> bucket_base, chunk_base ---------------
__global__ __launch_bounds__(NBP) void colscan_kernel(const int* __restrict__ partial,
    int* __restrict__ bucket_base, int* __restrict__ chunk_base) {
  __shared__ int sh[NBP];
  const int t = threadIdx.x;
  int tot = 0;
  if (t < NB)
    for (int blk = 0; blk < NBLK; ++blk) tot += partial[blk * PSTR + t];
  sh[t] = (t < NB) ? tot : 0;
  __syncthreads();
  for (int off = 1; off < NBP; off <<= 1) {
    int u = (t >= off) ? sh[t - off] : 0;
    __syncthreads();
    sh[t] += u;
    __syncthreads();
  }
  if (t < NB) {
    int base = sh[t] - tot;  // exclusive
    bucket_base[t] = base;
    int run = base;
    for (int blk = 0; blk < NBLK; ++blk) {
      chunk_base[blk * PSTR + t] = run;
      run += partial[blk * PSTR + t];
    }
  }
  if (t == NB - 1) bucket_base[NB] = sh[t];  // = E
}

// -------------------- K3: part (blocks 0..195) UNION feat (blocks 196..1758) ---------
__global__ __launch_bounds__(256, 6) void featpart_kernel(
    const float* __restrict__ x,
    const ushort* __restrict__ wf1hi, const ushort* __restrict__ wf1lo,
    const ushort* __restrict__ wf2hi, const ushort* __restrict__ wf2lo,
    const float* __restrict__ attn_l, const float* __restrict__ attn_r,
    ushort* __restrict__ ft_bf, float* __restrict__ a1, float* __restrict__ a2,
    const int* __restrict__ src, const int* __restrict__ dst,
    const int* __restrict__ chunk_base, int* __restrict__ ebuf) {
  extern __shared__ char smem[];
  const int bid = blockIdx.x;
  const int tid = threadIdx.x;

  if (bid < NBLK) {
    // ==== part: direct placement at precomputed per-(chunk,bucket) bases (no sort) ====
    int* curs = (int*)smem;          // [NB]
    const int e0 = bid * CHUNK, e1 = min(e0 + CHUNK, E);
    for (int k = tid; k < NB; k += 256) curs[k] = chunk_base[bid * PSTR + k];
    __syncthreads();
    for (int i = e0 + tid; i < e1; i += 256) {
      int s = src[i], d = dst[i];
      int pos = atomicAdd(&curs[((unsigned)d) >> 7], 1);
      ebuf[pos] = (s << 7) | (d & 127);
    }
    return;
  }

  // ======== feat: ft = lrelu(x@W1^T)@W2^T (bf16 hi/lo MFMA), a1/a2 reductions ========
  ushort* sXhi = (ushort*)smem;        // [FROWS][LDX]
  ushort* sXlo = sXhi + FROWS * LDX;
  const int w = tid >> 6, l = tid & 63;
  const int lr = l & 15, lg4 = l >> 4;
  const int rowBase = (bid - NBLK) * FROWS;

  for (int i = tid; i < FROWS * 32; i += 256) {
    int row = i >> 5, kc = i & 31;
    int g = rowBase + row;
    float4 v = make_float4(0.f, 0.f, 0.f, 0.f);
    if (g < N) v = reinterpret_cast<const float4*>(x)[g * 32 + kc];
    ushort4 hi, lo;
    hi.x = f2bf(v.x); lo.x = f2bf(v.x - bf2f(hi.x));
    hi.y = f2bf(v.y); lo.y = f2bf(v.y - bf2f(hi.y));
    hi.z = f2bf(v.z); lo.z = f2bf(v.z - bf2f(hi.z));
    hi.w = f2bf(v.w); lo.w = f2bf(v.w - bf2f(hi.w));
    *(ushort4*)&sXhi[row * LDX + kc * 4] = hi;
    *(ushort4*)&sXlo[row * LDX + kc * 4] = lo;
  }
  __syncthreads();

  f32x4 acc[2][2];
#pragma unroll
  for (int mi = 0; mi < 2; ++mi)
#pragma unroll
    for (int jj = 0; jj < 2; ++jj) acc[mi][jj] = (f32x4){0.f, 0.f, 0.f, 0.f};

  // ---- stage 1: h1 = x @ W1^T (B-frags streamed per ks from L2) ----
#pragma unroll
  for (int ks = 0; ks < 4; ++ks) {
    bf16x8 bh[2], bl[2], ah[2], al[2];
#pragma unroll
    for (int jj = 0; jj < 2; ++jj) {
      int off = ((ks * 8 + (2 * w + jj)) * 64 + l) * 8;
      bh[jj] = *(const bf16x8*)&wf1hi[off];
      bl[jj] = *(const bf16x8*)&wf1lo[off];
    }
#pragma unroll
    for (int mi = 0; mi < 2; ++mi) {
      int addr = (mi * 16 + lr) * LDX + ks * 32 + lg4 * 8;
      ah[mi] = *(const bf16x8*)&sXhi[addr];
      al[mi] = *(const bf16x8*)&sXlo[addr];
    }
#pragma unroll
    for (int mi = 0; mi < 2; ++mi)
#pragma unroll
      for (int jj = 0; jj < 2; ++jj) {
        acc[mi][jj] = __builtin_amdgcn_mfma_f32_16x16x32_bf16(ah[mi], bh[jj], acc[mi][jj], 0, 0, 0);
        acc[mi][jj] = __builtin_amdgcn_mfma_f32_16x16x32_bf16(ah[mi], bl[jj], acc[mi][jj], 0, 0, 0);
        acc[mi][jj] = __builtin_amdgcn_mfma_f32_16x16x32_bf16(al[mi], bh[jj], acc[mi][jj], 0, 0, 0);
      }
  }
  __syncthreads();  // all stage-1 LDS reads done before overwrite

  // write h2 = lrelu(h1) back to sX (hi/lo); D layout: row=4*(l>>4)+r, col=l&15
#pragma unroll
  for (int mi = 0; mi < 2; ++mi)
#pragma unroll
    for (int jj = 0; jj < 2; ++jj)
#pragma unroll
      for (int r = 0; r < 4; ++r) {
        float v = acc[mi][jj][r];
        v = v > 0.f ? v : ALPHA * v;
        int row = mi * 16 + lg4 * 4 + r;
        int col = w * 32 + jj * 16 + lr;
        ushort hv = f2bf(v);
        sXhi[row * LDX + col] = hv;
        sXlo[row * LDX + col] = f2bf(v - bf2f(hv));
      }
  __syncthreads();

#pragma unroll
  for (int mi = 0; mi < 2; ++mi)
#pragma unroll
    for (int jj = 0; jj < 2; ++jj) acc[mi][jj] = (f32x4){0.f, 0.f, 0.f, 0.f};

  // ---- stage 2: ft = h2 @ W2^T ----
#pragma unroll
  for (int ks = 0; ks < 4; ++ks) {
    bf16x8 bh[2], bl[2], ah[2], al[2];
#pragma unroll
    for (int jj = 0; jj < 2; ++jj) {
      int off = ((ks * 8 + (2 * w + jj)) * 64 + l) * 8;
      bh[jj] = *(const bf16x8*)&wf2hi[off];
      bl[jj] = *(const bf16x8*)&wf2lo[off];
    }
#pragma unroll
    for (int mi = 0; mi < 2; ++mi) {
      int addr = (mi * 16 + lr) * LDX + ks * 32 + lg4 * 8;
      ah[mi] = *(const bf16x8*)&sXhi[addr];
      al[mi] = *(const bf16x8*)&sXlo[addr];
    }
#pragma unroll
    for (int mi = 0; mi < 2; ++mi)
#pragma unroll
      for (int jj = 0; jj < 2; ++jj) {
        acc[mi][jj] = __builtin_amdgcn_mfma_f32_16x16x32_bf16(ah[mi], bh[jj], acc[mi][jj], 0, 0, 0);
        acc[mi][jj] = __builtin_amdgcn_mfma_f32_16x16x32_bf16(ah[mi], bl[jj], acc[mi][jj], 0, 0, 0);
        acc[mi][jj] = __builtin_amdgcn_mfma_f32_16x16x32_bf16(al[mi], bh[jj], acc[mi][jj], 0, 0, 0);
      }
  }

  // ---- epilogue: ft (bf16) + a1/a2 via 16-lane shuffle reduce over d ----
#pragma unroll
  for (int mi = 0; mi < 2; ++mi)
#pragma unroll
    for (int jj = 0; jj < 2; ++jj) {
      int h = 2 * w + jj;
      float alv = attn_l[h * 16 + lr], arv = attn_r[h * 16 + lr];
#pragma unroll
      for (int r = 0; r < 4; ++r) {
        float v = acc[mi][jj][r];
        int grow = rowBase + mi * 16 + lg4 * 4 + r;
        bool valid = grow < N;
        if (valid) ft_bf[grow * 128 + h * 16 + lr] = f2bf(v);
        float sl = v * alv, sr = v * arv;
#pragma unroll
        for (int off = 8; off; off >>= 1) {
          sl += __shfl_xor(sl, off, 16);
          sr += __shfl_xor(sr, off, 16);
        }
        if (valid && lr == 0) { a1[grow * 8 + h] = sl; a2[grow * 8 + h] = sr; }
      }
    }
}

// ---- K4: per-bucket fine sort + local CSR build (row_ptr derived here) --------------
__global__ __launch_bounds__(256) void fine_kernel(const int* __restrict__ ebuf,
    const int* __restrict__ bucket_base, int* __restrict__ row_ptr,
    int* __restrict__ col_src) {
  __shared__ int ldeg[BN], sc[BN], curs[BN];
  const int b = blockIdx.x, t = threadIdx.x;
  const int node0 = b * BN;
  const int nloc = min(BN, N - node0);
  const int bstart = bucket_base[b], bend = bucket_base[b + 1];
  if (t < BN) ldeg[t] = 0;
  __syncthreads();
  for (int i = bstart + t; i < bend; i += 256)
    atomicAdd(&ldeg[ebuf[i] & 127], 1);
  __syncthreads();
  if (t < BN) sc[t] = ldeg[t];
  __syncthreads();
#pragma unroll
  for (int off = 1; off < BN; off <<= 1) {
    int u = (t < BN && t >= off) ? sc[t - off] : 0;
    __syncthreads();
    if (t < BN) sc[t] += u;
    __syncthreads();
  }
  if (t < nloc) {
    int base = bstart + sc[t] - ldeg[t];
    row_ptr[node0 + t] = base;
    curs[t] = base;
  }
  if (b == NB - 1 && t == 0) row_ptr[N] = bend;
  __syncthreads();
  for (int i = bstart + t; i < bend; i += 256) {
    int pr = ebuf[i];
    int pos = atomicAdd(&curs[pr & 127], 1);
    col_src[pos] = pr >> 7;
  }
}

// -------------------- K5: single-pass softmax-aggregate ------------------------------
// 64-lane group per node. Phase A: lane t=(edge e=t>>3, head hA=t&7) computes each
// (e,h) logit/exp exactly ONCE. Phase B: broadcast p and src via shfl; lane t
// accumulates d-pair t*2 (head hB=t>>3). 8 gathers in flight.
__global__ __launch_bounds__(256) void agg_kernel(const int* __restrict__ row_ptr,
    const int* __restrict__ col_src, const ushort* __restrict__ ft_bf,
    const float* __restrict__ a1, const float* __restrict__ a2,
    float* __restrict__ out) {
  const int node = blockIdx.x * 4 + (threadIdx.x >> 6);
  if (node >= N) return;
  const int t = threadIdx.x & 63;
  const int eSlot = t >> 3;
  const int hA = t & 7;
  const int hB = t >> 3;
  const int start = row_ptr[node], end = row_ptr[node + 1];
  const float a2nA = a2[node * 8 + hA];

  float l = 0.f, acc0 = 0.f, acc1 = 0.f;
  for (int base = start; base < end; base += 8) {
    int rem = end - base; rem = rem > 8 ? 8 : rem;
    int idx = base + (eSlot < rem ? eSlot : rem - 1);
    int s = col_src[idx];
    float lg = a1[s * 8 + hA] + a2nA;
    lg = lg > 0.f ? lg : ALPHA * lg;
    float p = (eSlot < rem) ? __expf(lg) : 0.f;
#pragma unroll
    for (int e = 0; e < 8; ++e) {
      float pe = __shfl(p, e * 8 + hB);
      int se = __shfl(s, e * 8);
      ushort2 f = *(const ushort2*)&ft_bf[se * 128 + t * 2];
      l += pe;
      acc0 = fmaf(pe, bf2f(f.x), acc0);
      acc1 = fmaf(pe, bf2f(f.y), acc1);
    }
  }
  float inv = (end > start) ? 1.f / l : 0.f;
  *(float2*)&out[node * 128 + t * 2] = make_float2(acc0 * inv, acc1 * inv);
}

// -------------------- launch --------------------
extern "C" void kernel_launch(void* const* d_in, const int* in_sizes, int n_in,
                              void* d_out, int out_size, void* d_ws, size_t ws_size,
                              hipStream_t stream) {
  const float* x      = (const float*)d_in[0];
  const float* W1     = (const float*)d_in[1];
  const float* W2     = (const float*)d_in[2];
  const float* attn_l = (const float*)d_in[3];
  const float* attn_r = (const float*)d_in[4];
  const int*   edge   = (const int*)d_in[5];
  const int*   src    = edge;
  const int*   dst    = edge + E;
  float* out = (float*)d_out;

  char* ws = (char*)d_ws;
  ushort* ft_bf       = (ushort*)(ws);                 // 12,800,000 B
  float*  a1          = (float*) (ws + 12800000);      //  1,600,000 B
  float*  a2          = (float*) (ws + 14400000);      //  1,600,000 B
  int*    row_ptr     = (int*)   (ws + 16000000);      //    200,064 B (N+1 ints)
  int*    bucket_base = (int*)   (ws + 16200064);      //      1,600 B (392 ints)
  int*    col_src     = (int*)   (ws + 16201664);      //  3,200,000 B
  ushort* wf1hi       = (ushort*)(ws + 19401664);      //     32,768 B each
  ushort* wf1lo       = (ushort*)(ws + 19434432);
  ushort* wf2hi       = (ushort*)(ws + 19467200);
  ushort* wf2lo       = (ushort*)(ws + 19499968);
  int*    ebuf        = (int*)   (ws + 19532736);      //  3,200,000 B
  int*    partial     = (int*)   (ws + 22732736);      //    307,328 B (196x392 ints)
  int*    chunk_base  = (int*)   (ws + 23040064);      //    307,328 B -> end ~23.35 MB

  k1_kernel<<<NBLK + 16, 256, 0, stream>>>(W1, W2, wf1hi, wf1lo, wf2hi, wf2lo, dst, partial);
  colscan_kernel<<<1, NBP, 0, stream>>>(partial, bucket_base, chunk_base);
  featpart_kernel<<<NBLK + FEATB, 256, SMEMB, stream>>>(
      x, wf1hi, wf1lo, wf2hi, wf2lo, attn_l, attn_r, ft_bf, a1, a2,
      src, dst, chunk_base, ebuf);
  fine_kernel<<<NB, 256, 0, stream>>>(ebuf, bucket_base, row_ptr, col_src);
  agg_kernel<<<(N + 3) / 4, 256, 0, stream>>>(row_ptr, col_src, ft_bf, a1, a2, out);
}